// Round 9
// baseline (3958.097 us; speedup 1.0000x reference)
//
#include <hip/hip_runtime.h>
#include <math.h>

#define Bc 4
#define Nc 8192
#define NPOINTc 2048
#define NSAMPLEc 16
#define CINc 64
#define COUTc 128
#define FDIMc 67
#define NBUCK 128
#define EPSc 1e-5f

// ---------------------------------------------------------------- K0: |xyz|^2 (f32, rn-chain)
__global__ void sq_norm_kernel(const float* __restrict__ xyz, float* __restrict__ sn) {
    int i = blockIdx.x * blockDim.x + threadIdx.x;
    if (i < Bc * Nc) {
        float x = xyz[i * 3], y = xyz[i * 3 + 1], z = xyz[i * 3 + 2];
        sn[i] = __fadd_rn(__fadd_rn(__fmul_rn(x, x), __fmul_rn(y, y)), __fmul_rn(z, z));
    }
}

// ---------------------------------------------------------------- DPP lex-argmax step
// VALU-pipe cross-lane. Invalid-source lanes keep old value (bound_ctrl=false)
// -> self-compare no-op. Strict > keeps lowest index on tie.
template <int CTRL>
__device__ __forceinline__ void amax_dpp(float& bd, int& bi) {
    const int od_i = __builtin_amdgcn_update_dpp(__float_as_int(bd), __float_as_int(bd),
                                                 CTRL, 0xF, 0xF, false);
    const int oi   = __builtin_amdgcn_update_dpp(bi, bi, CTRL, 0xF, 0xF, false);
    const float od = __int_as_float(od_i);
    if (od > bd || (od == bd && oi < bi)) { bd = od; bi = oi; }
}

// ---------------------------------------------------------------- K1: FPS — 256 thr, 1 wave/SIMD
// One block/batch, 4 waves, 32 pts/thread. Per iteration: rn-chain distance
// update (exact reference semantics) -> 5-level per-thread (val,idx) tree ->
// 6-step DPP wave64 lex-argmax (lane 63) -> one barrier (parity-dbuf partials)
// -> lanes 0-3 + 2 DPP steps -> readlane(3) -> coords from LDS point cache.
__global__ __launch_bounds__(256, 1) void fps_kernel(const float* __restrict__ xyz,
                                                     int* __restrict__ cent,
                                                     float* __restrict__ newxyz) {
    const int b = blockIdx.x;
    const float* base = xyz + (size_t)b * Nc * 3;
    const int t = threadIdx.x;
    const int lane = t & 63, wid = t >> 6;   // 4 waves

    __shared__ float P[Nc * 3];              // 96 KB point cache
    __shared__ float pd[2][4];
    __shared__ int   pi[2][4];

    for (int e = t; e < Nc * 3; e += 256) P[e] = base[e];

    float X[32], Y[32], Z[32], D[32];
#pragma unroll
    for (int k = 0; k < 32; ++k) {
        const int n = t + (k << 8);
        X[k] = base[n * 3 + 0];
        Y[k] = base[n * 3 + 1];
        Z[k] = base[n * 3 + 2];
        D[k] = 1e10f;
    }
    if (t == 0) {
        cent[b * NPOINTc] = 0;
        float* o = newxyz + (size_t)b * NPOINTc * 3;
        o[0] = base[0]; o[1] = base[1]; o[2] = base[2];
    }
    __syncthreads();

    float cx = P[0], cy = P[1], cz = P[2];

    for (int it = 1; it < NPOINTc; ++it) {
        // --- distance update: exact f32 rn-chain, no FMA (reference semantics)
#pragma unroll
        for (int k = 0; k < 32; ++k) {
            const float dx = __fsub_rn(X[k], cx);
            const float dy = __fsub_rn(Y[k], cy);
            const float dz = __fsub_rn(Z[k], cz);
            const float d2 = __fadd_rn(__fadd_rn(__fmul_rn(dx, dx), __fmul_rn(dy, dy)),
                                       __fmul_rn(dz, dz));
            D[k] = fminf(D[k], d2);          // v_min_f32 (matches jnp.minimum, no NaNs)
        }
        // --- per-thread 5-level (val,idx) tree; left operand lower index,
        //     strict > on right preserves lowest-index tie-break
        float a0[16]; int x0[16];
#pragma unroll
        for (int k = 0; k < 16; ++k) {
            const bool g = D[2 * k + 1] > D[2 * k];
            a0[k] = g ? D[2 * k + 1] : D[2 * k];
            x0[k] = t + ((g ? (2 * k + 1) : (2 * k)) << 8);
        }
        float a1[8]; int x1[8];
#pragma unroll
        for (int k = 0; k < 8; ++k) {
            const bool g = a0[2 * k + 1] > a0[2 * k];
            a1[k] = g ? a0[2 * k + 1] : a0[2 * k];
            x1[k] = g ? x0[2 * k + 1] : x0[2 * k];
        }
        float a2[4]; int x2[4];
#pragma unroll
        for (int k = 0; k < 4; ++k) {
            const bool g = a1[2 * k + 1] > a1[2 * k];
            a2[k] = g ? a1[2 * k + 1] : a1[2 * k];
            x2[k] = g ? x1[2 * k + 1] : x1[2 * k];
        }
        float a3[2]; int x3[2];
#pragma unroll
        for (int k = 0; k < 2; ++k) {
            const bool g = a2[2 * k + 1] > a2[2 * k];
            a3[k] = g ? a2[2 * k + 1] : a2[2 * k];
            x3[k] = g ? x2[2 * k + 1] : x2[2 * k];
        }
        float bd = (a3[1] > a3[0]) ? a3[1] : a3[0];
        int   bi = (a3[1] > a3[0]) ? x3[1] : x3[0];

        // --- wave64 DPP lex-argmax; result lands in lane 63
        amax_dpp<0x111>(bd, bi);             // row_shr:1
        amax_dpp<0x112>(bd, bi);             // row_shr:2
        amax_dpp<0x114>(bd, bi);             // row_shr:4
        amax_dpp<0x118>(bd, bi);             // row_shr:8
        amax_dpp<0x142>(bd, bi);             // row_bcast:15
        amax_dpp<0x143>(bd, bi);             // row_bcast:31

        const int par = it & 1;
        if (lane == 63) { pd[par][wid] = bd; pi[par][wid] = bi; }
        __syncthreads();                     // the only barrier per iteration

        // --- cross-wave: lanes 0-3 load partials, 2 DPP steps -> lane 3
        float d4 = (lane < 4) ? pd[par][lane] : -INFINITY;
        int   i4 = (lane < 4) ? pi[par][lane] : 0x7fffffff;
        amax_dpp<0x111>(d4, i4);
        amax_dpp<0x112>(d4, i4);
        const int riv = __builtin_amdgcn_readlane(i4, 3);   // uniform winner index

        cx = P[riv * 3 + 0]; cy = P[riv * 3 + 1]; cz = P[riv * 3 + 2];

        if (t == 0) {                        // off the critical path
            cent[b * NPOINTc + it] = riv;
            float* o = newxyz + ((size_t)b * NPOINTc + it) * 3;
            o[0] = cx; o[1] = cy; o[2] = cz;
        }
    }
}

// ---------------------------------------------------------------- K2: KNN — wave-resident top-16
__global__ __launch_bounds__(64) void knn_kernel(const float* __restrict__ xyz,
                                                 const float* __restrict__ sn,
                                                 const int* __restrict__ cent,
                                                 int* __restrict__ knn) {
    const int g = blockIdx.x;                // b*NPOINT + m
    const int b = g >> 11;
    const int lane = threadIdx.x;
    const float* base = xyz + (size_t)b * Nc * 3;
    const float* snb = sn + (size_t)b * Nc;

    const int cm = cent[g];
    const float mx = base[cm * 3 + 0];
    const float my = base[cm * 3 + 1];
    const float mz = base[cm * 3 + 2];
    const float s1 = snb[cm];

    float dls[16];
    int   ils[16];
#pragma unroll
    for (int j = 0; j < 16; ++j) { dls[j] = INFINITY; ils[j] = -1; }

    for (int jj = 0; jj < Nc / 64; ++jj) {
        const int n = lane + (jj << 6);
        const float x = base[n * 3 + 0];
        const float y = base[n * 3 + 1];
        const float z = base[n * 3 + 2];
        const float dot = fmaf(z, mz, fmaf(y, my, __fmul_rn(x, mx)));
        float d = __fadd_rn(__fadd_rn(__fmul_rn(-2.0f, dot), s1), snb[n]);
        d = fmaxf(d, 0.0f);
        if (d < dls[15]) {                   // strict: equal dist keeps existing lower idx
            float cd = d; int ci = n;
#pragma unroll
            for (int j = 0; j < 16; ++j) {
                const bool less = cd < dls[j];
                const float td = less ? dls[j] : cd;
                const int   ti = less ? ils[j] : ci;
                dls[j] = less ? cd : dls[j];
                ils[j] = less ? ci : ils[j];
                cd = td; ci = ti;
            }
        }
    }

    __shared__ float ld[64][16];
    __shared__ int   li[64][16];
#pragma unroll
    for (int j = 0; j < 16; ++j) { ld[lane][j] = dls[j]; li[lane][j] = ils[j]; }

    int ptr = 0;
    int* out = knn + (size_t)g * NSAMPLEc;
    for (int r = 0; r < NSAMPLEc; ++r) {
        const float hd = ld[lane][ptr];
        const int   hi = li[lane][ptr];
        float vd = hd; int vi = hi;
#pragma unroll
        for (int off = 32; off > 0; off >>= 1) {
            const float od = __shfl_xor(vd, off, 64);
            const int   oi = __shfl_xor(vi, off, 64);
            if (od < vd || (od == vd && oi < vi)) { vd = od; vi = oi; }
        }
        if (hd == vd && hi == vi) ptr++;
        if (lane == r) out[r] = vi;
    }
}

// ---------------------------------------------------------------- staging helper (featT layout)
__device__ __forceinline__ void stage_featT(
        const float* __restrict__ px, const float* __restrict__ xyz,
        const float* __restrict__ newxyz, const int* __restrict__ knn,
        int g, int b, int t, float (*featT)[20], int* nidx, float* ctr) {
    if (t < 16) nidx[t] = knn[(size_t)g * NSAMPLEc + t];
    if (t < 3)  ctr[t] = newxyz[(size_t)g * 3 + t];
    __syncthreads();
    for (int e = t; e < 16 * FDIMc; e += 128) {
        const int s = e / FDIMc, i = e % FDIMc;
        float v;
        if (i < CINc) v = px[((size_t)b * Nc + nidx[s]) * CINc + i];
        else          v = __fsub_rn(xyz[((size_t)b * Nc + nidx[s]) * 3 + (i - CINc)], ctr[i - CINc]);
        featT[i][s] = v;
    }
    __syncthreads();
}

// ---------------------------------------------------------------- GEMM body (shared by K3 paths)
__device__ __forceinline__ void gemm_body(const float (*featT)[20], const float* __restrict__ W,
                                          float bc, int t, float* acc) {
#pragma unroll
    for (int r = 0; r < 16; ++r) acc[r] = bc;
    for (int i = 0; i < FDIMc; ++i) {
        const float w = W[i * COUTc + t];
        const float4* fr = (const float4*)featT[i];
        const float4 f0 = fr[0], f1 = fr[1], f2 = fr[2], f3 = fr[3];
        acc[0]  = fmaf(f0.x, w, acc[0]);  acc[1]  = fmaf(f0.y, w, acc[1]);
        acc[2]  = fmaf(f0.z, w, acc[2]);  acc[3]  = fmaf(f0.w, w, acc[3]);
        acc[4]  = fmaf(f1.x, w, acc[4]);  acc[5]  = fmaf(f1.y, w, acc[5]);
        acc[6]  = fmaf(f1.z, w, acc[6]);  acc[7]  = fmaf(f1.w, w, acc[7]);
        acc[8]  = fmaf(f2.x, w, acc[8]);  acc[9]  = fmaf(f2.y, w, acc[9]);
        acc[10] = fmaf(f2.z, w, acc[10]); acc[11] = fmaf(f2.w, w, acc[11]);
        acc[12] = fmaf(f3.x, w, acc[12]); acc[13] = fmaf(f3.y, w, acc[13]);
        acc[14] = fmaf(f3.z, w, acc[14]); acc[15] = fmaf(f3.w, w, acc[15]);
    }
}

// ---------------------------------------------------------------- K3: GEMM + BN stats (+h extremes)
// Also stores per-(group,channel) max/min of h: since BN is per-channel affine
// and ReLU monotone, max_s relu(sc*h+sh) == relu(sc*(sc>0?maxh:minh)+sh) EXACTLY.
__global__ __launch_bounds__(128) void gemm_stats_kernel(
        const float* __restrict__ px, const float* __restrict__ xyz,
        const float* __restrict__ newxyz, const int* __restrict__ knn,
        const float* __restrict__ W, const float* __restrict__ bias,
        float* __restrict__ bsum, float* __restrict__ bsq,
        float* __restrict__ hmax, float* __restrict__ hmin) {
    const int g = blockIdx.x;
    const int b = g >> 11;
    const int t = threadIdx.x;

    __shared__ __align__(16) float featT[FDIMc][20];
    __shared__ int nidx[16];
    __shared__ float ctr[3];
    stage_featT(px, xyz, newxyz, knn, g, b, t, featT, nidx, ctr);

    float acc[16];
    gemm_body(featT, W, bias[t], t, acc);

    float s = 0.f, q = 0.f, mx = acc[0], mn = acc[0];
#pragma unroll
    for (int r = 0; r < 16; ++r) { s += acc[r]; q += acc[r] * acc[r]; }
#pragma unroll
    for (int r = 1; r < 16; ++r) { mx = fmaxf(mx, acc[r]); mn = fminf(mn, acc[r]); }
    atomicAdd(&bsum[(g & (NBUCK - 1)) * COUTc + t], s);
    atomicAdd(&bsq [(g & (NBUCK - 1)) * COUTc + t], q);
    if (hmax) { hmax[(size_t)g * COUTc + t] = mx; hmin[(size_t)g * COUTc + t] = mn; }
}

// ---------------------------------------------------------------- K4: finalize stats
__global__ void stats_finalize_kernel(const float* __restrict__ bsum,
                                      const float* __restrict__ bsq,
                                      const float* __restrict__ gamma,
                                      const float* __restrict__ beta,
                                      float* __restrict__ scsh) {
    const int c = threadIdx.x;  // 128
    float S = 0.f, Q = 0.f;
    for (int k = 0; k < NBUCK; ++k) { S += bsum[k * COUTc + c]; Q += bsq[k * COUTc + c]; }
    const float cnt = (float)(Bc * NPOINTc * NSAMPLEc);
    const float mu = S / cnt;
    const float var = Q / cnt - mu * mu;
    const float sc = gamma[c] / sqrtf(var + EPSc);
    scsh[c] = sc;
    scsh[COUTc + c] = beta[c] - mu * sc;
}

// ---------------------------------------------------------------- K5fused: elementwise finalize
__global__ __launch_bounds__(256) void finalize_out_kernel(
        const float* __restrict__ hmax, const float* __restrict__ hmin,
        const float* __restrict__ scsh, float* __restrict__ out) {
    const int i = blockIdx.x * 256 + threadIdx.x;   // 8192*128 total
    const int c = i & (COUTc - 1);
    const float sc = scsh[c], sh = scsh[COUTc + c];
    const float sel = (sc > 0.f) ? hmax[i] : hmin[i];
    out[i] = fmaxf(fmaf(sel, sc, sh), 0.0f);
}

// ---------------------------------------------------------------- K5legacy: full GEMM + BN + ReLU + max
__global__ __launch_bounds__(128) void gemm_out_kernel(
        const float* __restrict__ px, const float* __restrict__ xyz,
        const float* __restrict__ newxyz, const int* __restrict__ knn,
        const float* __restrict__ W, const float* __restrict__ bias,
        const float* __restrict__ scsh, float* __restrict__ out) {
    const int g = blockIdx.x;
    const int b = g >> 11;
    const int t = threadIdx.x;

    __shared__ __align__(16) float featT[FDIMc][20];
    __shared__ int nidx[16];
    __shared__ float ctr[3];
    stage_featT(px, xyz, newxyz, knn, g, b, t, featT, nidx, ctr);

    float acc[16];
    gemm_body(featT, W, bias[t], t, acc);

    const float sc = scsh[t], sh = scsh[COUTc + t];
    float m = -INFINITY;
#pragma unroll
    for (int r = 0; r < 16; ++r) {
        const float v = fmaxf(fmaf(acc[r], sc, sh), 0.0f);
        m = fmaxf(m, v);
    }
    out[(size_t)g * COUTc + t] = m;
}

// ---------------------------------------------------------------- launch
extern "C" void kernel_launch(void* const* d_in, const int* in_sizes, int n_in,
                              void* d_out, int out_size, void* d_ws, size_t ws_size,
                              hipStream_t stream) {
    const float* px    = (const float*)d_in[0];
    const float* xyz   = (const float*)d_in[1];
    const float* W     = (const float*)d_in[2];
    const float* bias  = (const float*)d_in[3];
    const float* gamma = (const float*)d_in[4];
    const float* beta  = (const float*)d_in[5];

    float* out_px = (float*)d_out;                                  // (B,NPOINT,128)
    float* out_nx = out_px + (size_t)Bc * NPOINTc * COUTc;          // (B,NPOINT,3)

    char* w0 = (char*)d_ws;
    char* w = w0;
    int*   cent = (int*)w;    w += (size_t)Bc * NPOINTc * 4;
    float* sn   = (float*)w;  w += (size_t)Bc * Nc * 4;
    int*   knn  = (int*)w;    w += (size_t)Bc * NPOINTc * NSAMPLEc * 4;
    float* bsum = (float*)w;  w += (size_t)NBUCK * COUTc * 4;
    float* bsq  = (float*)w;  w += (size_t)NBUCK * COUTc * 4;
    float* scsh = (float*)w;  w += 2 * COUTc * 4;
    float* hmax = (float*)w;  w += (size_t)Bc * NPOINTc * COUTc * 4;
    float* hmin = (float*)w;  w += (size_t)Bc * NPOINTc * COUTc * 4;
    const bool fused = ((size_t)(w - w0) <= ws_size);

    hipMemsetAsync(bsum, 0, (size_t)NBUCK * COUTc * 4 * 2, stream);

    sq_norm_kernel<<<(Bc * Nc + 255) / 256, 256, 0, stream>>>(xyz, sn);
    fps_kernel<<<Bc, 256, 0, stream>>>(xyz, cent, out_nx);
    knn_kernel<<<Bc * NPOINTc, 64, 0, stream>>>(xyz, sn, cent, knn);
    gemm_stats_kernel<<<Bc * NPOINTc, 128, 0, stream>>>(px, xyz, out_nx, knn, W, bias,
                                                        bsum, bsq,
                                                        fused ? hmax : nullptr,
                                                        fused ? hmin : nullptr);
    stats_finalize_kernel<<<1, 128, 0, stream>>>(bsum, bsq, gamma, beta, scsh);
    if (fused) {
        finalize_out_kernel<<<(Bc * NPOINTc * COUTc) / 256, 256, 0, stream>>>(hmax, hmin, scsh, out_px);
    } else {
        gemm_out_kernel<<<Bc * NPOINTc, 128, 0, stream>>>(px, xyz, out_nx, knn, W, bias, scsh, out_px);
    }
}

// Round 10
// 3523.581 us; speedup vs baseline: 1.1233x; 1.1233x over previous
//
#include <hip/hip_runtime.h>
#include <math.h>

#define Bc 4
#define Nc 8192
#define NPOINTc 2048
#define NSAMPLEc 16
#define CINc 64
#define COUTc 128
#define FDIMc 67
#define NBUCK 128
#define EPSc 1e-5f

// ---------------------------------------------------------------- K0: |xyz|^2 (f32, rn-chain)
__global__ void sq_norm_kernel(const float* __restrict__ xyz, float* __restrict__ sn) {
    int i = blockIdx.x * blockDim.x + threadIdx.x;
    if (i < Bc * Nc) {
        float x = xyz[i * 3], y = xyz[i * 3 + 1], z = xyz[i * 3 + 2];
        sn[i] = __fadd_rn(__fadd_rn(__fmul_rn(x, x), __fmul_rn(y, y)), __fmul_rn(z, z));
    }
}

// ---------------------------------------------------------------- DPP lex-argmax step
// VALU-pipe cross-lane. Invalid-source lanes keep old value (bound_ctrl=false)
// -> self-compare no-op. Strict > keeps lowest index on tie.
template <int CTRL>
__device__ __forceinline__ void amax_dpp(float& bd, int& bi) {
    const int od_i = __builtin_amdgcn_update_dpp(__float_as_int(bd), __float_as_int(bd),
                                                 CTRL, 0xF, 0xF, false);
    const int oi   = __builtin_amdgcn_update_dpp(bi, bi, CTRL, 0xF, 0xF, false);
    const float od = __int_as_float(od_i);
    if (od > bd || (od == bd && oi < bi)) { bd = od; bi = oi; }
}

// ---------------------------------------------------------------- K1: FPS — 1024 thr, 4 waves/SIMD
// One block/batch, 16 waves, 8 pts/thread. 4 waves/SIMD interleave the
// dependency-bound segments (tree, DPP chain, LDS reads) that r9's 1-wave/SIMD
// config exposed. Per iteration: rn-chain distance update (exact reference
// semantics) -> 3-level per-thread (val,idx) tree -> 6-step DPP wave64
// lex-argmax (lane 63) -> one barrier (parity-dbuf partials) -> lanes 0-15 +
// 4 DPP steps -> readlane(15) -> winner coords from LDS point cache.
__global__ __launch_bounds__(1024, 1) void fps_kernel(const float* __restrict__ xyz,
                                                      int* __restrict__ cent,
                                                      float* __restrict__ newxyz) {
    const int b = blockIdx.x;
    const float* base = xyz + (size_t)b * Nc * 3;
    const int t = threadIdx.x;
    const int lane = t & 63, wid = t >> 6;   // 16 waves

    __shared__ float P[Nc * 3];              // 96 KB point cache
    __shared__ float pd[2][16];
    __shared__ int   pi[2][16];

    for (int e = t; e < Nc * 3; e += 1024) P[e] = base[e];

    float X[8], Y[8], Z[8], D[8];
#pragma unroll
    for (int k = 0; k < 8; ++k) {
        const int n = t + (k << 10);
        X[k] = base[n * 3 + 0];
        Y[k] = base[n * 3 + 1];
        Z[k] = base[n * 3 + 2];
        D[k] = 1e10f;
    }
    if (t == 0) {
        cent[b * NPOINTc] = 0;
        float* o = newxyz + (size_t)b * NPOINTc * 3;
        o[0] = base[0]; o[1] = base[1]; o[2] = base[2];
    }
    __syncthreads();

    float cx = P[0], cy = P[1], cz = P[2];

    for (int it = 1; it < NPOINTc; ++it) {
        // --- distance update: exact f32 rn-chain, no FMA (reference semantics)
#pragma unroll
        for (int k = 0; k < 8; ++k) {
            const float dx = __fsub_rn(X[k], cx);
            const float dy = __fsub_rn(Y[k], cy);
            const float dz = __fsub_rn(Z[k], cz);
            const float d2 = __fadd_rn(__fadd_rn(__fmul_rn(dx, dx), __fmul_rn(dy, dy)),
                                       __fmul_rn(dz, dz));
            D[k] = fminf(D[k], d2);          // v_min_f32 (matches jnp.minimum, no NaNs)
        }
        // --- per-thread 3-level (val,idx) tree; left operand lower index,
        //     strict > on right preserves lowest-index tie-break
        float a0[4]; int x0[4];
#pragma unroll
        for (int k = 0; k < 4; ++k) {
            const bool g = D[2 * k + 1] > D[2 * k];
            a0[k] = g ? D[2 * k + 1] : D[2 * k];
            x0[k] = t + ((g ? (2 * k + 1) : (2 * k)) << 10);
        }
        float a1[2]; int x1[2];
#pragma unroll
        for (int k = 0; k < 2; ++k) {
            const bool g = a0[2 * k + 1] > a0[2 * k];
            a1[k] = g ? a0[2 * k + 1] : a0[2 * k];
            x1[k] = g ? x0[2 * k + 1] : x0[2 * k];
        }
        float bd = (a1[1] > a1[0]) ? a1[1] : a1[0];
        int   bi = (a1[1] > a1[0]) ? x1[1] : x1[0];

        // --- wave64 DPP lex-argmax; result lands in lane 63
        amax_dpp<0x111>(bd, bi);             // row_shr:1
        amax_dpp<0x112>(bd, bi);             // row_shr:2
        amax_dpp<0x114>(bd, bi);             // row_shr:4
        amax_dpp<0x118>(bd, bi);             // row_shr:8
        amax_dpp<0x142>(bd, bi);             // row_bcast:15
        amax_dpp<0x143>(bd, bi);             // row_bcast:31

        const int par = it & 1;
        if (lane == 63) { pd[par][wid] = bd; pi[par][wid] = bi; }
        __syncthreads();                     // the only barrier per iteration

        // --- cross-wave: lanes 0-15 load the 16 partials, 4 DPP steps -> lane 15
        float d16 = (lane < 16) ? pd[par][lane] : -INFINITY;
        int   i16 = (lane < 16) ? pi[par][lane] : 0x7fffffff;
        amax_dpp<0x111>(d16, i16);
        amax_dpp<0x112>(d16, i16);
        amax_dpp<0x114>(d16, i16);
        amax_dpp<0x118>(d16, i16);
        const int riv = __builtin_amdgcn_readlane(i16, 15);   // uniform winner index

        cx = P[riv * 3 + 0]; cy = P[riv * 3 + 1]; cz = P[riv * 3 + 2];

        if (t == 0) {                        // off the critical path
            cent[b * NPOINTc + it] = riv;
            float* o = newxyz + ((size_t)b * NPOINTc + it) * 3;
            o[0] = cx; o[1] = cy; o[2] = cz;
        }
    }
}

// ---------------------------------------------------------------- K2: KNN — wave-resident top-16
__global__ __launch_bounds__(64) void knn_kernel(const float* __restrict__ xyz,
                                                 const float* __restrict__ sn,
                                                 const int* __restrict__ cent,
                                                 int* __restrict__ knn) {
    const int g = blockIdx.x;                // b*NPOINT + m
    const int b = g >> 11;
    const int lane = threadIdx.x;
    const float* base = xyz + (size_t)b * Nc * 3;
    const float* snb = sn + (size_t)b * Nc;

    const int cm = cent[g];
    const float mx = base[cm * 3 + 0];
    const float my = base[cm * 3 + 1];
    const float mz = base[cm * 3 + 2];
    const float s1 = snb[cm];

    float dls[16];
    int   ils[16];
#pragma unroll
    for (int j = 0; j < 16; ++j) { dls[j] = INFINITY; ils[j] = -1; }

    for (int jj = 0; jj < Nc / 64; ++jj) {
        const int n = lane + (jj << 6);
        const float x = base[n * 3 + 0];
        const float y = base[n * 3 + 1];
        const float z = base[n * 3 + 2];
        const float dot = fmaf(z, mz, fmaf(y, my, __fmul_rn(x, mx)));
        float d = __fadd_rn(__fadd_rn(__fmul_rn(-2.0f, dot), s1), snb[n]);
        d = fmaxf(d, 0.0f);
        if (d < dls[15]) {                   // strict: equal dist keeps existing lower idx
            float cd = d; int ci = n;
#pragma unroll
            for (int j = 0; j < 16; ++j) {
                const bool less = cd < dls[j];
                const float td = less ? dls[j] : cd;
                const int   ti = less ? ils[j] : ci;
                dls[j] = less ? cd : dls[j];
                ils[j] = less ? ci : ils[j];
                cd = td; ci = ti;
            }
        }
    }

    __shared__ float ld[64][16];
    __shared__ int   li[64][16];
#pragma unroll
    for (int j = 0; j < 16; ++j) { ld[lane][j] = dls[j]; li[lane][j] = ils[j]; }

    int ptr = 0;
    int* out = knn + (size_t)g * NSAMPLEc;
    for (int r = 0; r < NSAMPLEc; ++r) {
        const float hd = ld[lane][ptr];
        const int   hi = li[lane][ptr];
        float vd = hd; int vi = hi;
#pragma unroll
        for (int off = 32; off > 0; off >>= 1) {
            const float od = __shfl_xor(vd, off, 64);
            const int   oi = __shfl_xor(vi, off, 64);
            if (od < vd || (od == vd && oi < vi)) { vd = od; vi = oi; }
        }
        if (hd == vd && hi == vi) ptr++;
        if (lane == r) out[r] = vi;
    }
}

// ---------------------------------------------------------------- staging helper (featT layout)
__device__ __forceinline__ void stage_featT(
        const float* __restrict__ px, const float* __restrict__ xyz,
        const float* __restrict__ newxyz, const int* __restrict__ knn,
        int g, int b, int t, float (*featT)[20], int* nidx, float* ctr) {
    if (t < 16) nidx[t] = knn[(size_t)g * NSAMPLEc + t];
    if (t < 3)  ctr[t] = newxyz[(size_t)g * 3 + t];
    __syncthreads();
    for (int e = t; e < 16 * FDIMc; e += 128) {
        const int s = e / FDIMc, i = e % FDIMc;
        float v;
        if (i < CINc) v = px[((size_t)b * Nc + nidx[s]) * CINc + i];
        else          v = __fsub_rn(xyz[((size_t)b * Nc + nidx[s]) * 3 + (i - CINc)], ctr[i - CINc]);
        featT[i][s] = v;
    }
    __syncthreads();
}

// ---------------------------------------------------------------- GEMM body
__device__ __forceinline__ void gemm_body(const float (*featT)[20], const float* __restrict__ W,
                                          float bc, int t, float* acc) {
#pragma unroll
    for (int r = 0; r < 16; ++r) acc[r] = bc;
    for (int i = 0; i < FDIMc; ++i) {
        const float w = W[i * COUTc + t];
        const float4* fr = (const float4*)featT[i];
        const float4 f0 = fr[0], f1 = fr[1], f2 = fr[2], f3 = fr[3];
        acc[0]  = fmaf(f0.x, w, acc[0]);  acc[1]  = fmaf(f0.y, w, acc[1]);
        acc[2]  = fmaf(f0.z, w, acc[2]);  acc[3]  = fmaf(f0.w, w, acc[3]);
        acc[4]  = fmaf(f1.x, w, acc[4]);  acc[5]  = fmaf(f1.y, w, acc[5]);
        acc[6]  = fmaf(f1.z, w, acc[6]);  acc[7]  = fmaf(f1.w, w, acc[7]);
        acc[8]  = fmaf(f2.x, w, acc[8]);  acc[9]  = fmaf(f2.y, w, acc[9]);
        acc[10] = fmaf(f2.z, w, acc[10]); acc[11] = fmaf(f2.w, w, acc[11]);
        acc[12] = fmaf(f3.x, w, acc[12]); acc[13] = fmaf(f3.y, w, acc[13]);
        acc[14] = fmaf(f3.z, w, acc[14]); acc[15] = fmaf(f3.w, w, acc[15]);
    }
}

// ---------------------------------------------------------------- K3: GEMM + BN stats (+h extremes)
// BN is per-channel affine, ReLU monotone:
// max_s relu(sc*h+sh) == relu(sc*(sc>0?maxh:minh)+sh) EXACTLY.
__global__ __launch_bounds__(128) void gemm_stats_kernel(
        const float* __restrict__ px, const float* __restrict__ xyz,
        const float* __restrict__ newxyz, const int* __restrict__ knn,
        const float* __restrict__ W, const float* __restrict__ bias,
        float* __restrict__ bsum, float* __restrict__ bsq,
        float* __restrict__ hmax, float* __restrict__ hmin) {
    const int g = blockIdx.x;
    const int b = g >> 11;
    const int t = threadIdx.x;

    __shared__ __align__(16) float featT[FDIMc][20];
    __shared__ int nidx[16];
    __shared__ float ctr[3];
    stage_featT(px, xyz, newxyz, knn, g, b, t, featT, nidx, ctr);

    float acc[16];
    gemm_body(featT, W, bias[t], t, acc);

    float s = 0.f, q = 0.f, mx = acc[0], mn = acc[0];
#pragma unroll
    for (int r = 0; r < 16; ++r) { s += acc[r]; q += acc[r] * acc[r]; }
#pragma unroll
    for (int r = 1; r < 16; ++r) { mx = fmaxf(mx, acc[r]); mn = fminf(mn, acc[r]); }
    atomicAdd(&bsum[(g & (NBUCK - 1)) * COUTc + t], s);
    atomicAdd(&bsq [(g & (NBUCK - 1)) * COUTc + t], q);
    if (hmax) { hmax[(size_t)g * COUTc + t] = mx; hmin[(size_t)g * COUTc + t] = mn; }
}

// ---------------------------------------------------------------- K4: finalize stats
__global__ void stats_finalize_kernel(const float* __restrict__ bsum,
                                      const float* __restrict__ bsq,
                                      const float* __restrict__ gamma,
                                      const float* __restrict__ beta,
                                      float* __restrict__ scsh) {
    const int c = threadIdx.x;  // 128
    float S = 0.f, Q = 0.f;
    for (int k = 0; k < NBUCK; ++k) { S += bsum[k * COUTc + c]; Q += bsq[k * COUTc + c]; }
    const float cnt = (float)(Bc * NPOINTc * NSAMPLEc);
    const float mu = S / cnt;
    const float var = Q / cnt - mu * mu;
    const float sc = gamma[c] / sqrtf(var + EPSc);
    scsh[c] = sc;
    scsh[COUTc + c] = beta[c] - mu * sc;
}

// ---------------------------------------------------------------- K5fused: elementwise finalize
__global__ __launch_bounds__(256) void finalize_out_kernel(
        const float* __restrict__ hmax, const float* __restrict__ hmin,
        const float* __restrict__ scsh, float* __restrict__ out) {
    const int i = blockIdx.x * 256 + threadIdx.x;   // 8192*128 total
    const int c = i & (COUTc - 1);
    const float sc = scsh[c], sh = scsh[COUTc + c];
    const float sel = (sc > 0.f) ? hmax[i] : hmin[i];
    out[i] = fmaxf(fmaf(sel, sc, sh), 0.0f);
}

// ---------------------------------------------------------------- K5legacy: full GEMM + BN + ReLU + max
__global__ __launch_bounds__(128) void gemm_out_kernel(
        const float* __restrict__ px, const float* __restrict__ xyz,
        const float* __restrict__ newxyz, const int* __restrict__ knn,
        const float* __restrict__ W, const float* __restrict__ bias,
        const float* __restrict__ scsh, float* __restrict__ out) {
    const int g = blockIdx.x;
    const int b = g >> 11;
    const int t = threadIdx.x;

    __shared__ __align__(16) float featT[FDIMc][20];
    __shared__ int nidx[16];
    __shared__ float ctr[3];
    stage_featT(px, xyz, newxyz, knn, g, b, t, featT, nidx, ctr);

    float acc[16];
    gemm_body(featT, W, bias[t], t, acc);

    const float sc = scsh[t], sh = scsh[COUTc + t];
    float m = -INFINITY;
#pragma unroll
    for (int r = 0; r < 16; ++r) {
        const float v = fmaxf(fmaf(acc[r], sc, sh), 0.0f);
        m = fmaxf(m, v);
    }
    out[(size_t)g * COUTc + t] = m;
}

// ---------------------------------------------------------------- launch
extern "C" void kernel_launch(void* const* d_in, const int* in_sizes, int n_in,
                              void* d_out, int out_size, void* d_ws, size_t ws_size,
                              hipStream_t stream) {
    const float* px    = (const float*)d_in[0];
    const float* xyz   = (const float*)d_in[1];
    const float* W     = (const float*)d_in[2];
    const float* bias  = (const float*)d_in[3];
    const float* gamma = (const float*)d_in[4];
    const float* beta  = (const float*)d_in[5];

    float* out_px = (float*)d_out;                                  // (B,NPOINT,128)
    float* out_nx = out_px + (size_t)Bc * NPOINTc * COUTc;          // (B,NPOINT,3)

    char* w0 = (char*)d_ws;
    char* w = w0;
    int*   cent = (int*)w;    w += (size_t)Bc * NPOINTc * 4;
    float* sn   = (float*)w;  w += (size_t)Bc * Nc * 4;
    int*   knn  = (int*)w;    w += (size_t)Bc * NPOINTc * NSAMPLEc * 4;
    float* bsum = (float*)w;  w += (size_t)NBUCK * COUTc * 4;
    float* bsq  = (float*)w;  w += (size_t)NBUCK * COUTc * 4;
    float* scsh = (float*)w;  w += 2 * COUTc * 4;
    float* hmax = (float*)w;  w += (size_t)Bc * NPOINTc * COUTc * 4;
    float* hmin = (float*)w;  w += (size_t)Bc * NPOINTc * COUTc * 4;
    const bool fused = ((size_t)(w - w0) <= ws_size);

    hipMemsetAsync(bsum, 0, (size_t)NBUCK * COUTc * 4 * 2, stream);

    sq_norm_kernel<<<(Bc * Nc + 255) / 256, 256, 0, stream>>>(xyz, sn);
    fps_kernel<<<Bc, 1024, 0, stream>>>(xyz, cent, out_nx);
    knn_kernel<<<Bc * NPOINTc, 64, 0, stream>>>(xyz, sn, cent, knn);
    gemm_stats_kernel<<<Bc * NPOINTc, 128, 0, stream>>>(px, xyz, out_nx, knn, W, bias,
                                                        bsum, bsq,
                                                        fused ? hmax : nullptr,
                                                        fused ? hmin : nullptr);
    stats_finalize_kernel<<<1, 128, 0, stream>>>(bsum, bsq, gamma, beta, scsh);
    if (fused) {
        finalize_out_kernel<<<(Bc * NPOINTc * COUTc) / 256, 256, 0, stream>>>(hmax, hmin, scsh, out_px);
    } else {
        gemm_out_kernel<<<Bc * NPOINTc, 128, 0, stream>>>(px, xyz, out_nx, knn, W, bias, scsh, out_px);
    }
}

// Round 11
// 2671.308 us; speedup vs baseline: 1.4817x; 1.3190x over previous
//
#include <hip/hip_runtime.h>
#include <math.h>

#define Bc 4
#define Nc 8192
#define NPOINTc 2048
#define NSAMPLEc 16
#define CINc 64
#define COUTc 128
#define FDIMc 67
#define NBUCK 128
#define EPSc 1e-5f

typedef unsigned long long u64;

// ---------------------------------------------------------------- K0: |xyz|^2 (f32, rn-chain)
__global__ void sq_norm_kernel(const float* __restrict__ xyz, float* __restrict__ sn) {
    int i = blockIdx.x * blockDim.x + threadIdx.x;
    if (i < Bc * Nc) {
        float x = xyz[i * 3], y = xyz[i * 3 + 1], z = xyz[i * 3 + 2];
        sn[i] = __fadd_rn(__fadd_rn(__fmul_rn(x, x), __fmul_rn(y, y)), __fmul_rn(z, z));
    }
}

// ---------------------------------------------------------------- packed-u64 DPP max step
// key = (f32bits(dist) << 32) | ~idx. dist >= 0 -> bit order == value order;
// equal dist -> larger ~idx == lower idx wins. So lex-argmax == u64 max.
// bound_ctrl=false + old=own value -> invalid lanes self-compare (no-op).
template <int CTRL>
__device__ __forceinline__ void kmax_dpp(u64& key) {
    const unsigned lo = (unsigned)key, hi = (unsigned)(key >> 32);
    const unsigned olo = (unsigned)__builtin_amdgcn_update_dpp((int)lo, (int)lo, CTRL, 0xF, 0xF, false);
    const unsigned ohi = (unsigned)__builtin_amdgcn_update_dpp((int)hi, (int)hi, CTRL, 0xF, 0xF, false);
    const u64 okey = ((u64)ohi << 32) | olo;
    key = (okey > key) ? okey : key;
}

// ---------------------------------------------------------------- K1: FPS — 512 thr, LDS-only loop
// One block/batch, 8 waves, 16 pts/thread. Key change vs r8: NO global stores
// inside the loop — winners buffered in LDS WIN[], written back coalesced after
// the loop. The per-iteration barrier therefore only drains lgkmcnt (LDS, ~30cy)
// instead of vmcnt (global store retire, ~300-600cy convoy on wave 0).
// Reduction: per-thread (val,idx) tree (bit-identical to r8) -> pack u64 ->
// 6 DPP max steps (lane 63) -> barrier -> 8 partials -> 3 DPP steps -> lane 7.
__global__ __launch_bounds__(512) void fps_kernel(const float* __restrict__ xyz,
                                                  int* __restrict__ cent,
                                                  float* __restrict__ newxyz) {
    const int b = blockIdx.x;
    const float* base = xyz + (size_t)b * Nc * 3;
    const int t = threadIdx.x;
    const int lane = t & 63, wid = t >> 6;   // 8 waves

    __shared__ float P[Nc * 3];              // 96 KB point cache
    __shared__ u64   pk[2][8];               // parity-dbuf packed partials
    __shared__ int   WIN[NPOINTc];           // 8 KB winner buffer

    for (int e = t; e < Nc * 3; e += 512) P[e] = base[e];

    float X[16], Y[16], Z[16], D[16];
#pragma unroll
    for (int k = 0; k < 16; ++k) {
        const int n = t + (k << 9);
        X[k] = base[n * 3 + 0];
        Y[k] = base[n * 3 + 1];
        Z[k] = base[n * 3 + 2];
        D[k] = 1e10f;
    }
    if (t == 0) WIN[0] = 0;
    __syncthreads();

    float cx = P[0], cy = P[1], cz = P[2];

    for (int it = 1; it < NPOINTc; ++it) {
        // --- distance update: exact f32 rn-chain, no FMA (reference semantics)
#pragma unroll
        for (int k = 0; k < 16; ++k) {
            const float dx = __fsub_rn(X[k], cx);
            const float dy = __fsub_rn(Y[k], cy);
            const float dz = __fsub_rn(Z[k], cz);
            const float d2 = __fadd_rn(__fadd_rn(__fmul_rn(dx, dx), __fmul_rn(dy, dy)),
                                       __fmul_rn(dz, dz));
            D[k] = fminf(D[k], d2);          // v_min_f32 (matches jnp.minimum, no NaNs)
        }
        // --- per-thread 4-level (val,idx) tree; left operand lower index,
        //     strict > on right preserves lowest-index tie-break (r8-proven)
        float a0[8]; int x0[8];
#pragma unroll
        for (int k = 0; k < 8; ++k) {
            const bool g = D[2 * k + 1] > D[2 * k];
            a0[k] = g ? D[2 * k + 1] : D[2 * k];
            x0[k] = t + ((g ? (2 * k + 1) : (2 * k)) << 9);
        }
        float a1[4]; int x1[4];
#pragma unroll
        for (int k = 0; k < 4; ++k) {
            const bool g = a0[2 * k + 1] > a0[2 * k];
            a1[k] = g ? a0[2 * k + 1] : a0[2 * k];
            x1[k] = g ? x0[2 * k + 1] : x0[2 * k];
        }
        float a2[2]; int x2[2];
#pragma unroll
        for (int k = 0; k < 2; ++k) {
            const bool g = a1[2 * k + 1] > a1[2 * k];
            a2[k] = g ? a1[2 * k + 1] : a1[2 * k];
            x2[k] = g ? x1[2 * k + 1] : x1[2 * k];
        }
        const bool gf = a2[1] > a2[0];
        const float bd = gf ? a2[1] : a2[0];
        const int   bi = gf ? x2[1] : x2[0];

        // --- pack and wave64 DPP max; result lands in lane 63
        u64 key = ((u64)__float_as_uint(bd) << 32) | (unsigned)(~bi);
        kmax_dpp<0x111>(key);                // row_shr:1
        kmax_dpp<0x112>(key);                // row_shr:2
        kmax_dpp<0x114>(key);                // row_shr:4
        kmax_dpp<0x118>(key);                // row_shr:8
        kmax_dpp<0x142>(key);                // row_bcast:15
        kmax_dpp<0x143>(key);                // row_bcast:31

        const int par = it & 1;
        if (lane == 63) pk[par][wid] = key;
        __syncthreads();                     // drains lgkmcnt only (no VMEM in loop)

        // --- cross-wave: lanes 0-7 take the 8 partials, 3 DPP steps -> lane 7
        u64 k8 = pk[par][lane & 7];
        if (lane >= 8) k8 = 0;               // identity: loses to any real key
        kmax_dpp<0x111>(k8);
        kmax_dpp<0x112>(k8);
        kmax_dpp<0x114>(k8);
        const unsigned lo7 = (unsigned)__builtin_amdgcn_readlane((int)(unsigned)k8, 7);
        const int riv = (int)~lo7;           // uniform winner index

        cx = P[riv * 3 + 0]; cy = P[riv * 3 + 1]; cz = P[riv * 3 + 2];
        if (t == 0) WIN[it] = riv;           // LDS only
    }
    __syncthreads();

    // --- one-time coalesced writeback
    for (int e = t; e < NPOINTc; e += 512) {
        const int wv = WIN[e];
        cent[b * NPOINTc + e] = wv;
        float* o = newxyz + ((size_t)b * NPOINTc + e) * 3;
        o[0] = P[wv * 3 + 0]; o[1] = P[wv * 3 + 1]; o[2] = P[wv * 3 + 2];
    }
}

// ---------------------------------------------------------------- K2: KNN — wave-resident top-16
__global__ __launch_bounds__(64) void knn_kernel(const float* __restrict__ xyz,
                                                 const float* __restrict__ sn,
                                                 const int* __restrict__ cent,
                                                 int* __restrict__ knn) {
    const int g = blockIdx.x;                // b*NPOINT + m
    const int b = g >> 11;
    const int lane = threadIdx.x;
    const float* base = xyz + (size_t)b * Nc * 3;
    const float* snb = sn + (size_t)b * Nc;

    const int cm = cent[g];
    const float mx = base[cm * 3 + 0];
    const float my = base[cm * 3 + 1];
    const float mz = base[cm * 3 + 2];
    const float s1 = snb[cm];

    float dls[16];
    int   ils[16];
#pragma unroll
    for (int j = 0; j < 16; ++j) { dls[j] = INFINITY; ils[j] = -1; }

    for (int jj = 0; jj < Nc / 64; ++jj) {
        const int n = lane + (jj << 6);
        const float x = base[n * 3 + 0];
        const float y = base[n * 3 + 1];
        const float z = base[n * 3 + 2];
        const float dot = fmaf(z, mz, fmaf(y, my, __fmul_rn(x, mx)));
        float d = __fadd_rn(__fadd_rn(__fmul_rn(-2.0f, dot), s1), snb[n]);
        d = fmaxf(d, 0.0f);
        if (d < dls[15]) {                   // strict: equal dist keeps existing lower idx
            float cd = d; int ci = n;
#pragma unroll
            for (int j = 0; j < 16; ++j) {
                const bool less = cd < dls[j];
                const float td = less ? dls[j] : cd;
                const int   ti = less ? ils[j] : ci;
                dls[j] = less ? cd : dls[j];
                ils[j] = less ? ci : ils[j];
                cd = td; ci = ti;
            }
        }
    }

    __shared__ float ld[64][16];
    __shared__ int   li[64][16];
#pragma unroll
    for (int j = 0; j < 16; ++j) { ld[lane][j] = dls[j]; li[lane][j] = ils[j]; }

    int ptr = 0;
    int* out = knn + (size_t)g * NSAMPLEc;
    for (int r = 0; r < NSAMPLEc; ++r) {
        const float hd = ld[lane][ptr];
        const int   hi = li[lane][ptr];
        float vd = hd; int vi = hi;
#pragma unroll
        for (int off = 32; off > 0; off >>= 1) {
            const float od = __shfl_xor(vd, off, 64);
            const int   oi = __shfl_xor(vi, off, 64);
            if (od < vd || (od == vd && oi < vi)) { vd = od; vi = oi; }
        }
        if (hd == vd && hi == vi) ptr++;
        if (lane == r) out[r] = vi;
    }
}

// ---------------------------------------------------------------- staging helper (featT layout)
__device__ __forceinline__ void stage_featT(
        const float* __restrict__ px, const float* __restrict__ xyz,
        const float* __restrict__ newxyz, const int* __restrict__ knn,
        int g, int b, int t, float (*featT)[20], int* nidx, float* ctr) {
    if (t < 16) nidx[t] = knn[(size_t)g * NSAMPLEc + t];
    if (t < 3)  ctr[t] = newxyz[(size_t)g * 3 + t];
    __syncthreads();
    for (int e = t; e < 16 * FDIMc; e += 128) {
        const int s = e / FDIMc, i = e % FDIMc;
        float v;
        if (i < CINc) v = px[((size_t)b * Nc + nidx[s]) * CINc + i];
        else          v = __fsub_rn(xyz[((size_t)b * Nc + nidx[s]) * 3 + (i - CINc)], ctr[i - CINc]);
        featT[i][s] = v;
    }
    __syncthreads();
}

// ---------------------------------------------------------------- GEMM body
__device__ __forceinline__ void gemm_body(const float (*featT)[20], const float* __restrict__ W,
                                          float bc, int t, float* acc) {
#pragma unroll
    for (int r = 0; r < 16; ++r) acc[r] = bc;
    for (int i = 0; i < FDIMc; ++i) {
        const float w = W[i * COUTc + t];
        const float4* fr = (const float4*)featT[i];
        const float4 f0 = fr[0], f1 = fr[1], f2 = fr[2], f3 = fr[3];
        acc[0]  = fmaf(f0.x, w, acc[0]);  acc[1]  = fmaf(f0.y, w, acc[1]);
        acc[2]  = fmaf(f0.z, w, acc[2]);  acc[3]  = fmaf(f0.w, w, acc[3]);
        acc[4]  = fmaf(f1.x, w, acc[4]);  acc[5]  = fmaf(f1.y, w, acc[5]);
        acc[6]  = fmaf(f1.z, w, acc[6]);  acc[7]  = fmaf(f1.w, w, acc[7]);
        acc[8]  = fmaf(f2.x, w, acc[8]);  acc[9]  = fmaf(f2.y, w, acc[9]);
        acc[10] = fmaf(f2.z, w, acc[10]); acc[11] = fmaf(f2.w, w, acc[11]);
        acc[12] = fmaf(f3.x, w, acc[12]); acc[13] = fmaf(f3.y, w, acc[13]);
        acc[14] = fmaf(f3.z, w, acc[14]); acc[15] = fmaf(f3.w, w, acc[15]);
    }
}

// ---------------------------------------------------------------- K3: GEMM + BN stats (+h extremes)
// BN is per-channel affine, ReLU monotone:
// max_s relu(sc*h+sh) == relu(sc*(sc>0?maxh:minh)+sh) EXACTLY.
__global__ __launch_bounds__(128) void gemm_stats_kernel(
        const float* __restrict__ px, const float* __restrict__ xyz,
        const float* __restrict__ newxyz, const int* __restrict__ knn,
        const float* __restrict__ W, const float* __restrict__ bias,
        float* __restrict__ bsum, float* __restrict__ bsq,
        float* __restrict__ hmax, float* __restrict__ hmin) {
    const int g = blockIdx.x;
    const int b = g >> 11;
    const int t = threadIdx.x;

    __shared__ __align__(16) float featT[FDIMc][20];
    __shared__ int nidx[16];
    __shared__ float ctr[3];
    stage_featT(px, xyz, newxyz, knn, g, b, t, featT, nidx, ctr);

    float acc[16];
    gemm_body(featT, W, bias[t], t, acc);

    float s = 0.f, q = 0.f, mx = acc[0], mn = acc[0];
#pragma unroll
    for (int r = 0; r < 16; ++r) { s += acc[r]; q += acc[r] * acc[r]; }
#pragma unroll
    for (int r = 1; r < 16; ++r) { mx = fmaxf(mx, acc[r]); mn = fminf(mn, acc[r]); }
    atomicAdd(&bsum[(g & (NBUCK - 1)) * COUTc + t], s);
    atomicAdd(&bsq [(g & (NBUCK - 1)) * COUTc + t], q);
    if (hmax) { hmax[(size_t)g * COUTc + t] = mx; hmin[(size_t)g * COUTc + t] = mn; }
}

// ---------------------------------------------------------------- K4: finalize stats
__global__ void stats_finalize_kernel(const float* __restrict__ bsum,
                                      const float* __restrict__ bsq,
                                      const float* __restrict__ gamma,
                                      const float* __restrict__ beta,
                                      float* __restrict__ scsh) {
    const int c = threadIdx.x;  // 128
    float S = 0.f, Q = 0.f;
    for (int k = 0; k < NBUCK; ++k) { S += bsum[k * COUTc + c]; Q += bsq[k * COUTc + c]; }
    const float cnt = (float)(Bc * NPOINTc * NSAMPLEc);
    const float mu = S / cnt;
    const float var = Q / cnt - mu * mu;
    const float sc = gamma[c] / sqrtf(var + EPSc);
    scsh[c] = sc;
    scsh[COUTc + c] = beta[c] - mu * sc;
}

// ---------------------------------------------------------------- K5fused: elementwise finalize
__global__ __launch_bounds__(256) void finalize_out_kernel(
        const float* __restrict__ hmax, const float* __restrict__ hmin,
        const float* __restrict__ scsh, float* __restrict__ out) {
    const int i = blockIdx.x * 256 + threadIdx.x;   // 8192*128 total
    const int c = i & (COUTc - 1);
    const float sc = scsh[c], sh = scsh[COUTc + c];
    const float sel = (sc > 0.f) ? hmax[i] : hmin[i];
    out[i] = fmaxf(fmaf(sel, sc, sh), 0.0f);
}

// ---------------------------------------------------------------- K5legacy: full GEMM + BN + ReLU + max
__global__ __launch_bounds__(128) void gemm_out_kernel(
        const float* __restrict__ px, const float* __restrict__ xyz,
        const float* __restrict__ newxyz, const int* __restrict__ knn,
        const float* __restrict__ W, const float* __restrict__ bias,
        const float* __restrict__ scsh, float* __restrict__ out) {
    const int g = blockIdx.x;
    const int b = g >> 11;
    const int t = threadIdx.x;

    __shared__ __align__(16) float featT[FDIMc][20];
    __shared__ int nidx[16];
    __shared__ float ctr[3];
    stage_featT(px, xyz, newxyz, knn, g, b, t, featT, nidx, ctr);

    float acc[16];
    gemm_body(featT, W, bias[t], t, acc);

    const float sc = scsh[t], sh = scsh[COUTc + t];
    float m = -INFINITY;
#pragma unroll
    for (int r = 0; r < 16; ++r) {
        const float v = fmaxf(fmaf(acc[r], sc, sh), 0.0f);
        m = fmaxf(m, v);
    }
    out[(size_t)g * COUTc + t] = m;
}

// ---------------------------------------------------------------- launch
extern "C" void kernel_launch(void* const* d_in, const int* in_sizes, int n_in,
                              void* d_out, int out_size, void* d_ws, size_t ws_size,
                              hipStream_t stream) {
    const float* px    = (const float*)d_in[0];
    const float* xyz   = (const float*)d_in[1];
    const float* W     = (const float*)d_in[2];
    const float* bias  = (const float*)d_in[3];
    const float* gamma = (const float*)d_in[4];
    const float* beta  = (const float*)d_in[5];

    float* out_px = (float*)d_out;                                  // (B,NPOINT,128)
    float* out_nx = out_px + (size_t)Bc * NPOINTc * COUTc;          // (B,NPOINT,3)

    char* w0 = (char*)d_ws;
    char* w = w0;
    int*   cent = (int*)w;    w += (size_t)Bc * NPOINTc * 4;
    float* sn   = (float*)w;  w += (size_t)Bc * Nc * 4;
    int*   knn  = (int*)w;    w += (size_t)Bc * NPOINTc * NSAMPLEc * 4;
    float* bsum = (float*)w;  w += (size_t)NBUCK * COUTc * 4;
    float* bsq  = (float*)w;  w += (size_t)NBUCK * COUTc * 4;
    float* scsh = (float*)w;  w += 2 * COUTc * 4;
    float* hmax = (float*)w;  w += (size_t)Bc * NPOINTc * COUTc * 4;
    float* hmin = (float*)w;  w += (size_t)Bc * NPOINTc * COUTc * 4;
    const bool fused = ((size_t)(w - w0) <= ws_size);

    hipMemsetAsync(bsum, 0, (size_t)NBUCK * COUTc * 4 * 2, stream);

    sq_norm_kernel<<<(Bc * Nc + 255) / 256, 256, 0, stream>>>(xyz, sn);
    fps_kernel<<<Bc, 512, 0, stream>>>(xyz, cent, out_nx);
    knn_kernel<<<Bc * NPOINTc, 64, 0, stream>>>(xyz, sn, cent, knn);
    gemm_stats_kernel<<<Bc * NPOINTc, 128, 0, stream>>>(px, xyz, out_nx, knn, W, bias,
                                                        bsum, bsq,
                                                        fused ? hmax : nullptr,
                                                        fused ? hmin : nullptr);
    stats_finalize_kernel<<<1, 128, 0, stream>>>(bsum, bsq, gamma, beta, scsh);
    if (fused) {
        finalize_out_kernel<<<(Bc * NPOINTc * COUTc) / 256, 256, 0, stream>>>(hmax, hmin, scsh, out_px);
    } else {
        gemm_out_kernel<<<Bc * NPOINTc, 128, 0, stream>>>(px, xyz, out_nx, knn, W, bias, scsh, out_px);
    }
}